// Round 6
// baseline (517.612 us; speedup 1.0000x reference)
//
#include <hip/hip_runtime.h>
#include <math.h>

#define HW 64

typedef unsigned long long u64;

// hot raster record: one 64-B scalar load (s_load_dwordx16)
// f[0..8] = w coeffs (wx,wy,wc ×3 edges), f[9..11] = zx,zy,zc (z linear in px,py),
// f[12] = epsf, f[13] = epsz
struct FaceRec {
  float f[16];
};

// exact-geometry record: f32 image coords + camera z (the reference's f32 inputs
// to the f64 rasterization). g0={v0x,v0y,v1x,v1y} g1={v2x,v2y,z0,z1} g2={z2,-,-,-}
struct FaceGeo {
  float v0x, v0y, v1x, v1y;
  float v2x, v2y, z0, z1;
  float z2, pad0, pad1, pad2;
};

__global__ void k_zero(float* __restrict__ vnorm, int nvn,
                       u64* __restrict__ rowmask, int maskwords,
                       int* __restrict__ cnt) {
  int i = blockIdx.x * blockDim.x + threadIdx.x;
  int total = gridDim.x * blockDim.x;
  for (int j = i; j < nvn; j += total) vnorm[j] = 0.f;
  for (int j = i; j < maskwords; j += total) rowmask[j] = 0ull;
  if (i == 0) cnt[0] = 0;
}

__global__ void k_facepre(const float* __restrict__ vert,
                          const float* __restrict__ rot,
                          const float* __restrict__ trans,
                          const int* __restrict__ faces,
                          FaceRec* __restrict__ frec,
                          FaceGeo* __restrict__ fgeo,
                          u64* __restrict__ rowmask, int WPR,
                          float* __restrict__ vnorm,
                          int B, int V, int F) {
  int i = blockIdx.x * blockDim.x + threadIdx.x;
  if (i >= B * F) return;
  int b = i / F, f = i % F;
  const float* R = rot + b * 9;
  const float* t = trans + b * 3;
  int vid[3] = {faces[f * 3 + 0], faces[f * 3 + 1], faces[f * 3 + 2]};
  float cx[3], cy[3], cz[3];
#pragma unroll
  for (int k = 0; k < 3; ++k) {   // inline camera transform (same f32 ordering as ref)
    const float* vv = vert + (size_t)(b * V + vid[k]) * 3;
    float x = vv[0], y = vv[1], z = vv[2];
    cx[k] = ((x * R[0] + y * R[1]) + z * R[2]) + t[0];
    cy[k] = ((x * R[3] + y * R[4]) + z * R[5]) + t[1];
    cz[k] = ((x * R[6] + y * R[7]) + z * R[8]) + t[2];
  }
  float c0z = cz[0], c1z = cz[1], c2z = cz[2];
  // f32 image coords (matches reference vs_img = xy/z in f32)
  float v0x = cx[0] / c0z, v0y = cy[0] / c0z;
  float v1x = cx[1] / c1z, v1y = cy[1] / c1z;
  float v2x = cx[2] / c2z, v2y = cy[2] / c2z;
  FaceGeo ge;
  ge.v0x = v0x; ge.v0y = v0y; ge.v1x = v1x; ge.v1y = v1y;
  ge.v2x = v2x; ge.v2y = v2y; ge.z0 = c0z; ge.z1 = c1z;
  ge.z2 = c2z; ge.pad0 = 0.f; ge.pad1 = 0.f; ge.pad2 = 0.f;
  fgeo[i] = ge;
  // f32 edge deltas (reference computes these in f32 before f64 promotion)
  float dx0 = v2x - v1x, dy0 = v2y - v1y;   // edge(v1,v2), anchor v1
  float dx1 = v0x - v2x, dy1 = v0y - v2y;   // edge(v2,v0), anchor v2
  float dx2 = v1x - v0x, dy2 = v1y - v0y;   // edge(v0,v1), anchor v0
  float A = dx2 * (v2y - v0y) - dy2 * (v2x - v0x);
  if (fabsf(A) < 1e-8f) A = 1e-8f;
  double invA = 1.0 / (double)A;
  // premultiplied barycentric coefficients: w_e = wx*px + wy*py + wc
  double wx0 = -(double)dy0 * invA, wy0 = (double)dx0 * invA;
  double wc0 = ((double)dy0 * (double)v1x - (double)dx0 * (double)v1y) * invA;
  double wx1 = -(double)dy1 * invA, wy1 = (double)dx1 * invA;
  double wc1 = ((double)dy1 * (double)v2x - (double)dx1 * (double)v2y) * invA;
  double wx2 = -(double)dy2 * invA, wy2 = (double)dx2 * invA;
  double wc2 = ((double)dy2 * (double)v0x - (double)dx2 * (double)v0y) * invA;
  // z is linear: z = zx*px + zy*py + zc
  double zx = wx0 * (double)c0z + wx1 * (double)c1z + wx2 * (double)c2z;
  double zy = wy0 * (double)c0z + wy1 * (double)c1z + wy2 * (double)c2z;
  double zc = wc0 * (double)c0z + wc1 * (double)c1z + wc2 * (double)c2z;
  double m0 = fabs(wx0) + fabs(wy0) + fabs(wc0);
  double m1 = fabs(wx1) + fabs(wy1) + fabs(wc1);
  double m2 = fabs(wx2) + fabs(wy2) + fabs(wc2);
  double mm = fmax(fmax(m0, m1), m2);
  float epsf = fmaxf((float)(6e-7 * mm), 3e-7f);  // margin over f32 coeff+eval error
  float epsz = fmaxf((float)(1e-6 * (fabs(zx) + fabs(zy) + fabs(zc))), 1e-9f);
  FaceRec fr;
  fr.f[0] = (float)wx0; fr.f[1] = (float)wy0; fr.f[2] = (float)wc0;
  fr.f[3] = (float)wx1; fr.f[4] = (float)wy1; fr.f[5] = (float)wc1;
  fr.f[6] = (float)wx2; fr.f[7] = (float)wy2; fr.f[8] = (float)wc2;
  fr.f[9] = (float)zx;  fr.f[10] = (float)zy; fr.f[11] = (float)zc;
  fr.f[12] = epsf; fr.f[13] = epsz; fr.f[14] = 0.f; fr.f[15] = 0.f;
  frec[i] = fr;
  // conservative y-row interval of the band-dilated triangle (superset of all
  // faces that can be f64-inside OR contribute prob on the row)
  float band = fmaxf(0.302f, 1.5f * epsf);
  float ylo = -1.01f, yhi = 1.01f;
  bool empty = false;
  float wyA[3] = {fr.f[1], fr.f[4], fr.f[7]};
  float gA[3]  = {fr.f[2] + fabsf(fr.f[0]) + band,
                  fr.f[5] + fabsf(fr.f[3]) + band,
                  fr.f[8] + fabsf(fr.f[6]) + band};
#pragma unroll
  for (int e = 0; e < 3; ++e) {
    float wy = wyA[e], g = gA[e];
    if (wy > 1e-30f)       ylo = fmaxf(ylo, -g / wy);
    else if (wy < -1e-30f) yhi = fminf(yhi, -g / wy);
    else                   empty |= (g < 0.f);
    empty |= (g + fabsf(wy) < 0.f);
  }
  if (!empty && ylo <= yhi) {
    int r0 = max(0, (int)floorf((ylo + 1.0f) * 31.5f) - 1);
    int r1 = min(63, (int)ceilf((yhi + 1.0f) * 31.5f) + 1);
    u64 bit = 1ull << (f & 63);
    int word = f >> 6;
    for (int r = r0; r <= r1; ++r)
      atomicOr(&rowmask[((size_t)(b * 64 + r)) * WPR + word], bit);
  }
  // face normal -> vertex normal scatter (f32 atomics)
  float e1x = cx[1] - cx[0], e1y = cy[1] - cy[0], e1z = cz[1] - cz[0];
  float e2x = cx[2] - cx[0], e2y = cy[2] - cy[0], e2z = cz[2] - cz[0];
  float nx = e1y * e2z - e1z * e2y;
  float ny = e1z * e2x - e1x * e2z;
  float nz = e1x * e2y - e1y * e2x;
#pragma unroll
  for (int k = 0; k < 3; ++k) {
    float* vn = vnorm + (size_t)(b * V + vid[k]) * 3;
    atomicAdd(vn + 0, nx); atomicAdd(vn + 1, ny); atomicAdd(vn + 2, nz);
  }
}

// bitmask -> compact ascending per-row face list. One wave per row.
__global__ __launch_bounds__(256) void k_rowlist(
    const u64* __restrict__ rowmask, int WPR,
    int* __restrict__ rowlist, int* __restrict__ rowcnt, int F) {
  int wid = __builtin_amdgcn_readfirstlane(threadIdx.x >> 6);
  int rowg = blockIdx.x * 4 + wid;              // global row = b*64 + r
  int lane = threadIdx.x & 63;
  const u64* rm = rowmask + (size_t)rowg * WPR;
  int w0i = 2 * lane, w1i = 2 * lane + 1;       // lane order == word order
  u64 m0 = (w0i < WPR) ? rm[w0i] : 0ull;
  u64 m1 = (w1i < WPR) ? rm[w1i] : 0ull;
  int c = __popcll(m0) + __popcll(m1);
  int off = c;                                   // inclusive prefix
  for (int d = 1; d < 64; d <<= 1) {
    int t = __shfl_up(off, d);
    if (lane >= d) off += t;
  }
  int pos = off - c;                             // exclusive
  int* out = rowlist + (size_t)rowg * F;
  u64 m = m0;
  int base = w0i << 6;
  while (m) { int t = __builtin_ctzll(m); m &= m - 1; out[pos++] = base + t; }
  m = m1; base = w1i << 6;
  while (m) { int t = __builtin_ctzll(m); m &= m - 1; out[pos++] = base + t; }
  if (lane == 63) rowcnt[rowg] = off;
}

// exact f64 winner recompute + gather-interpolate + output write (not improb)
__device__ void write_winner(const FaceGeo* __restrict__ fgeo,
                             const int* __restrict__ faces,
                             const float* __restrict__ vnorm,
                             const float* __restrict__ attribs,
                             float* __restrict__ out, int P,
                             int b, int V, int F, int pix,
                             int best, bool covered) {
  int p = b * (HW * HW) + pix;
  float imn[3] = {0.f, 0.f, 0.f};
  float ima[3] = {0.f, 0.f, 0.f};
  if (covered) {
    int x = pix & 63, y = pix >> 6;
    const double step = 2.0 / 63.0;
    double px = (x == HW - 1) ? 1.0 : (x * step - 1.0);
    double py = (y == HW - 1) ? 1.0 : (y * step - 1.0);
    FaceGeo g = fgeo[(size_t)b * F + best];
    float dx0 = g.v2x - g.v1x, dy0 = g.v2y - g.v1y;
    float dx1 = g.v0x - g.v2x, dy1 = g.v0y - g.v2y;
    float dx2 = g.v1x - g.v0x, dy2 = g.v1y - g.v0y;
    float A = dx2 * (g.v2y - g.v0y) - dy2 * (g.v2x - g.v0x);
    if (fabsf(A) < 1e-8f) A = 1e-8f;
    double invA = 1.0 / (double)A;
    double a0 = (double)dx0 * (py - (double)g.v1y) - (double)dy0 * (px - (double)g.v1x);
    double a1 = (double)dx1 * (py - (double)g.v2y) - (double)dy1 * (px - (double)g.v2x);
    double a2 = (double)dx2 * (py - (double)g.v0y) - (double)dy2 * (px - (double)g.v0x);
    double wk[3] = {a0 * invA, a1 * invA, a2 * invA};
    int vid[3] = {faces[best * 3 + 0], faces[best * 3 + 1], faces[best * 3 + 2]};
    double v[6] = {0, 0, 0, 0, 0, 0};
#pragma unroll
    for (int k = 0; k < 3; ++k) {
      const float* n = vnorm + (size_t)(b * V + vid[k]) * 3;
      float nx = n[0], ny = n[1], nz = n[2];
      float nrm = sqrtf(nx * nx + ny * ny + nz * nz) + 1e-10f;  // f32, like ref
      const float* at = attribs + (((size_t)(b * F + best)) * 3 + k) * 3;
      v[0] += wk[k] * (double)(nx / nrm);
      v[1] += wk[k] * (double)(ny / nrm);
      v[2] += wk[k] * (double)(nz / nrm);
      v[3] += wk[k] * (double)at[0];
      v[4] += wk[k] * (double)at[1];
      v[5] += wk[k] * (double)at[2];
    }
    double nn = sqrt(v[0] * v[0] + v[1] * v[1] + v[2] * v[2]) + 1e-10;
    imn[0] = (float)(v[0] / nn);
    imn[1] = (float)(v[1] / nn);
    imn[2] = (float)(v[2] / nn);
    ima[0] = (float)v[3]; ima[1] = (float)v[4]; ima[2] = (float)v[5];
  }
  float* o_n = out;
  float* o_a = out + (size_t)P * 3;
  float* o_p = out + (size_t)P * 6;
  float* o_i = o_p + P;
  o_n[(size_t)p * 3 + 0] = imn[0];
  o_n[(size_t)p * 3 + 1] = imn[1];
  o_n[(size_t)p * 3 + 2] = imn[2];
  o_a[(size_t)p * 3 + 0] = ima[0];
  o_a[(size_t)p * 3 + 1] = ima[1];
  o_a[(size_t)p * 3 + 2] = ima[2];
  o_i[p] = covered ? (float)best : -1.0f;
}

// one block per row; 4 waves quarter the row's list (batch-4 scalar prefetch),
// LDS combine, wave 0 finalizes (winner interp + improb + flag append)
__global__ __launch_bounds__(256) void k_raster(
    const FaceRec* __restrict__ frec,
    const int* __restrict__ rowlist, const int* __restrict__ rowcnt,
    const FaceGeo* __restrict__ fgeo,
    const int* __restrict__ faces,
    const float* __restrict__ vnorm,
    const float* __restrict__ attribs,
    float* __restrict__ out,
    int* __restrict__ cnt, int* __restrict__ list,
    int B, int V, int F) {
  __shared__ float4 comb[4][64];
  int rowg = blockIdx.x;                 // global row = b*64 + r
  int b = rowg >> 6, r = rowg & 63;
  int wid = __builtin_amdgcn_readfirstlane(threadIdx.x >> 6);
  int x = threadIdx.x & 63;
  int P = B * HW * HW;
  const double step = 2.0 / 63.0;
  double pxd = (x == HW - 1) ? 1.0 : (x * step - 1.0);
  double pyd = (r == HW - 1) ? 1.0 : (r * step - 1.0);
  float pxf = (float)pxd, pyf = (float)pyd;
  const FaceRec* __restrict__ fb = frec + (size_t)b * F;
  const int* __restrict__ rl = rowlist + (size_t)rowg * F;
  int n = rowcnt[rowg];
  int q = (n + 3) >> 2;
  int beg = wid * q;
  int end = min(n, beg + q);

  float zminf = INFINITY, weps = 0.f, lsum = 0.f;
  int best = 0;
  bool flag = false;

  for (int i = beg; i < end; i += 4) {
    int last = end - 1;
    int j0 = __builtin_amdgcn_readfirstlane(rl[i]);
    int j1 = __builtin_amdgcn_readfirstlane(rl[min(i + 1, last)]);
    int j2 = __builtin_amdgcn_readfirstlane(rl[min(i + 2, last)]);
    int j3 = __builtin_amdgcn_readfirstlane(rl[min(i + 3, last)]);
    // 4 independent 64-B scalar loads issued before any use -> one wait
    FaceRec r0 = fb[j0];
    FaceRec r1 = fb[j1];
    FaceRec r2 = fb[j2];
    FaceRec r3 = fb[j3];
    const FaceRec* rs[4] = {&r0, &r1, &r2, &r3};
    int js[4] = {j0, j1, j2, j3};
#pragma unroll
    for (int k = 0; k < 4; ++k) {
      if (i + k >= end) break;
      const FaceRec& fr = *rs[k];
      float w0 = fmaf(fr.f[0], pxf, fmaf(fr.f[1], pyf, fr.f[2]));
      float w1 = fmaf(fr.f[3], pxf, fmaf(fr.f[4], pyf, fr.f[5]));
      float w2 = fmaf(fr.f[6], pxf, fmaf(fr.f[7], pyf, fr.f[8]));
      float dmin = fminf(fminf(w0, w1), w2);
      if (dmin > -0.3f) {
        // clip(dmin/sigma,-30,0): dmin<=-0.3 contributes ~1e-13, skipped
        float tt = fminf(fmaxf(dmin * 100.0f, -30.0f), 0.0f);
        float pr = __expf(tt);               // inside -> tt=0 -> pr=1 exactly
        lsum += __logf(fmaf(-pr, 0.99999990f, 1.0f));
      }
      float epsf = fr.f[12], epsz = fr.f[13];
      if (dmin > -epsf) {
        float z = fmaf(fr.f[9], pxf, fmaf(fr.f[10], pyf, fr.f[11]));
        bool contend = (z < zminf + epsz + weps) & (z > -epsz);
        flag |= (fabsf(dmin) < epsf) & contend;           // inside-sign ambiguous
        flag |= (dmin >= 0.0f) & (fabsf(z) < epsz);       // z>0 boundary ambiguous
        flag |= (dmin >= 0.0f) & (z > 0.0f) &
                (fabsf(z - zminf) < epsz + weps);         // z-order ambiguous
        if ((dmin >= 0.0f) & (z > 0.0f) & (z < zminf)) {  // strict <: first-occurrence
          zminf = z; best = js[k]; weps = epsz;
        }
      }
    }
  }
  unsigned bestflag = (unsigned)best | (flag ? 0x80000000u : 0u);
  comb[wid][x] = make_float4(zminf, __uint_as_float(bestflag), lsum, weps);
  __syncthreads();
  if (wid == 0) {
    float zmin = INFINITY, we = 0.f, ls = 0.f;
    int bi = 0;
    bool fl = false;
#pragma unroll
    for (int wv = 0; wv < 4; ++wv) {       // ascending: preserves first-occurrence
      float4 qd = comb[wv][x];
      float z = qd.x;
      unsigned pb = __float_as_uint(qd.y);
      float e = qd.w;
      fl |= (pb >> 31) != 0;
      fl |= fabsf(z - zmin) < (e + we + 2e-6f);  // cross-quarter near-tie (INF-safe)
      if (z < zmin) { zmin = z; bi = (int)(pb & 0x7fffffffu); we = e; }
      ls += qd.z;
    }
    bool covered = (zmin < 1e38f);
    int pix = r * HW + x;
    write_winner(fgeo, faces, vnorm, attribs, out, P, b, V, F, pix, bi, covered);
    float* o_p = out + (size_t)P * 6;
    int p = b * (HW * HW) + pix;
    o_p[p] = 1.0f - __expf(ls);
    if (fl) {
      int s = atomicAdd(cnt, 1);
      list[s] = p;
    }
  }
}

// exact f64 re-argmin for flagged pixels: one wave per pixel over the row list
__global__ __launch_bounds__(256) void k_repair(
    const FaceGeo* __restrict__ fgeo,
    const int* __restrict__ faces,
    const float* __restrict__ vnorm,
    const float* __restrict__ attribs,
    const int* __restrict__ rowlist, const int* __restrict__ rowcnt,
    const int* __restrict__ cnt, const int* __restrict__ list,
    float* __restrict__ out, int B, int V, int F) {
  int P = B * HW * HW;
  int lane = threadIdx.x & 63;
  int wid = (blockIdx.x * blockDim.x + threadIdx.x) >> 6;
  int nwaves = (gridDim.x * blockDim.x) >> 6;
  int n = cnt[0];
  for (int i = wid; i < n; i += nwaves) {
    int p = list[i];
    int b = p >> 12;
    int pix = p & 4095;
    int x = pix & 63, y = pix >> 6;
    int rowg = (p >> 6);                 // b*64 + y
    const double step = 2.0 / 63.0;
    double px = (x == HW - 1) ? 1.0 : (x * step - 1.0);
    double py = (y == HW - 1) ? 1.0 : (y * step - 1.0);
    const int* rl = rowlist + (size_t)rowg * F;
    int m = rowcnt[rowg];
    const float4* g4 = (const float4*)(fgeo + (size_t)b * F);
    double zmin = INFINITY;
    int best = 0x7fffffff;
    for (int k = lane; k < m; k += 64) {   // lane-local ascending
      int f = rl[k];
      const float4* pg = g4 + (size_t)f * 3;
      float4 g0 = pg[0], g1 = pg[1], g2 = pg[2];
      float v0x = g0.x, v0y = g0.y, v1x = g0.z, v1y = g0.w;
      float v2x = g1.x, v2y = g1.y, c0z = g1.z, c1z = g1.w, c2z = g2.x;
      float dx0 = v2x - v1x, dy0 = v2y - v1y;
      float dx1 = v0x - v2x, dy1 = v0y - v2y;
      float dx2 = v1x - v0x, dy2 = v1y - v0y;
      float A = dx2 * (v2y - v0y) - dy2 * (v2x - v0x);
      if (fabsf(A) < 1e-8f) A = 1e-8f;
      double invA = 1.0 / (double)A;
      double a0 = (double)dx0 * (py - (double)v1y) - (double)dy0 * (px - (double)v1x);
      double a1 = (double)dx1 * (py - (double)v2y) - (double)dy1 * (px - (double)v2x);
      double a2 = (double)dx2 * (py - (double)v0y) - (double)dy2 * (px - (double)v0x);
      double w0 = a0 * invA, w1 = a1 * invA, w2 = a2 * invA;
      bool inside = (w0 >= 0.0) & (w1 >= 0.0) & (w2 >= 0.0);
      double z = (w0 * (double)c0z + w1 * (double)c1z) + w2 * (double)c2z;
      if (inside & (z > 0.0) & (z < zmin)) { zmin = z; best = f; }
    }
    // lexicographic (z, idx) wave reduce -> first-occurrence argmin
    for (int off = 32; off; off >>= 1) {
      double zo = __shfl_down(zmin, off);
      int bo = __shfl_down(best, off);
      if ((zo < zmin) || ((zo == zmin) && (bo < best))) { zmin = zo; best = bo; }
    }
    if (lane == 0) {
      bool covered = (zmin < 1e300);
      write_winner(fgeo, faces, vnorm, attribs, out, P, b, V, F, pix, best, covered);
    }
  }
}

extern "C" void kernel_launch(void* const* d_in, const int* in_sizes, int n_in,
                              void* d_out, int out_size, void* d_ws, size_t ws_size,
                              hipStream_t stream) {
  const float* vert    = (const float*)d_in[0];
  const int*   faces   = (const int*)d_in[1];
  const float* attribs = (const float*)d_in[2];
  const float* rot     = (const float*)d_in[3];
  const float* trans   = (const float*)d_in[4];
  int B = in_sizes[4] / 3;
  int V = in_sizes[0] / (3 * B);
  int F = in_sizes[1] / 3;
  int P = B * HW * HW;
  int NR = B * 64;                 // total rows
  int WPR = (F + 63) / 64;
  int maskwords = NR * WPR;

  char* w = (char*)d_ws;
  FaceRec* frec  = (FaceRec*)w;  w += sizeof(FaceRec) * (size_t)B * F;  // 64B-aligned
  FaceGeo* fgeo  = (FaceGeo*)w;  w += sizeof(FaceGeo) * (size_t)B * F;
  u64* rowmask   = (u64*)w;      w += 8u * (size_t)maskwords;
  int* rowlist   = (int*)w;      w += 4u * (size_t)NR * F;
  int* rowcnt    = (int*)w;      w += 4u * (size_t)NR;
  float* vnorm   = (float*)w;    w += 4u * 3 * (size_t)B * V;
  int* cnt       = (int*)w;      w += 4;
  int* list      = (int*)w;      w += 4u * (size_t)P;

  k_zero<<<128, 256, 0, stream>>>(vnorm, B * V * 3, rowmask, maskwords, cnt);
  k_facepre<<<(B * F + 255) / 256, 256, 0, stream>>>(
      vert, rot, trans, faces, frec, fgeo, rowmask, WPR, vnorm, B, V, F);
  k_rowlist<<<NR / 4, 256, 0, stream>>>(rowmask, WPR, rowlist, rowcnt, F);
  k_raster<<<NR, 256, 0, stream>>>(frec, rowlist, rowcnt, fgeo, faces, vnorm,
                                   attribs, (float*)d_out, cnt, list, B, V, F);
  k_repair<<<128, 256, 0, stream>>>(fgeo, faces, vnorm, attribs, rowlist, rowcnt,
                                    cnt, list, (float*)d_out, B, V, F);
}

// Round 7
// 352.332 us; speedup vs baseline: 1.4691x; 1.4691x over previous
//
#include <hip/hip_runtime.h>
#include <math.h>
#include <string.h>

#define HW 64
#define NC 8                 // face-list chunks per band (grid.y = NC+1, last = slivers)
#define SLIV_EPS 1e-4f

typedef unsigned long long u64;

// hot raster record, 64 B: q0={wx0,wy0,wc0,wx1} q1={wy1,wc1,wx2,wy2}
// q2={wc2,epsf,zx,zy} q3={zc,epsz,fid_bits,0}
struct FaceRec { float f[16]; };

// exact-geometry record (reference's f32 inputs to the f64 raster math)
struct FaceGeo {
  float v0x, v0y, v1x, v1y;
  float v2x, v2y, z0, z1;
  float z2, pad0, pad1, pad2;
};

// sliver record, 64 B: q0={invA_lo,invA_hi,v0x,v0y} q1={v1x,v1y,v2x,v2y}
// q2={z0,z1,z2,fid_bits} q3={r0r1_bits,0,0,0}
struct SlivRec { float g[16]; };

__global__ void k_zero(float* __restrict__ vnorm, int nvn,
                       u64* __restrict__ bandmask, int maskwords,
                       int* __restrict__ slivcnt, int B, int* __restrict__ cnt) {
  int i = blockIdx.x * blockDim.x + threadIdx.x;
  int total = gridDim.x * blockDim.x;
  for (int j = i; j < nvn; j += total) vnorm[j] = 0.f;
  for (int j = i; j < maskwords; j += total) bandmask[j] = 0ull;
  if (i < B) slivcnt[i] = 0;
  if (i == 0) cnt[0] = 0;
}

__global__ void k_facepre(const float* __restrict__ vert,
                          const float* __restrict__ rot,
                          const float* __restrict__ trans,
                          const int* __restrict__ faces,
                          FaceRec* __restrict__ frec,
                          FaceGeo* __restrict__ fgeo,
                          u64* __restrict__ bandmask, int WPR,
                          SlivRec* __restrict__ slivers, int* __restrict__ slivcnt,
                          float* __restrict__ vnorm,
                          int B, int V, int F) {
  int i = blockIdx.x * blockDim.x + threadIdx.x;
  if (i >= B * F) return;
  int b = i / F, f = i % F;
  const float* R = rot + b * 9;
  const float* t = trans + b * 3;
  int vid[3] = {faces[f * 3 + 0], faces[f * 3 + 1], faces[f * 3 + 2]};
  float cx[3], cy[3], cz[3];
#pragma unroll
  for (int k = 0; k < 3; ++k) {   // inline camera transform (ref's f32 op order)
    const float* vv = vert + (size_t)(b * V + vid[k]) * 3;
    float x = vv[0], y = vv[1], z = vv[2];
    cx[k] = ((x * R[0] + y * R[1]) + z * R[2]) + t[0];
    cy[k] = ((x * R[3] + y * R[4]) + z * R[5]) + t[1];
    cz[k] = ((x * R[6] + y * R[7]) + z * R[8]) + t[2];
  }
  float c0z = cz[0], c1z = cz[1], c2z = cz[2];
  float v0x = cx[0] / c0z, v0y = cy[0] / c0z;   // f32 image coords, like ref
  float v1x = cx[1] / c1z, v1y = cy[1] / c1z;
  float v2x = cx[2] / c2z, v2y = cy[2] / c2z;
  FaceGeo ge;
  ge.v0x = v0x; ge.v0y = v0y; ge.v1x = v1x; ge.v1y = v1y;
  ge.v2x = v2x; ge.v2y = v2y; ge.z0 = c0z; ge.z1 = c1z;
  ge.z2 = c2z; ge.pad0 = 0.f; ge.pad1 = 0.f; ge.pad2 = 0.f;
  fgeo[i] = ge;
  // f32 edge deltas (ref computes these in f32 before f64 promotion)
  float dx0 = v2x - v1x, dy0 = v2y - v1y;   // edge(v1,v2), anchor v1
  float dx1 = v0x - v2x, dy1 = v0y - v2y;   // edge(v2,v0), anchor v2
  float dx2 = v1x - v0x, dy2 = v1y - v0y;   // edge(v0,v1), anchor v0
  float A = dx2 * (v2y - v0y) - dy2 * (v2x - v0x);
  if (fabsf(A) < 1e-8f) A = 1e-8f;
  double invA = 1.0 / (double)A;
  // premultiplied barycentric coefficients: w_e = wx*px + wy*py + wc
  double wx0 = -(double)dy0 * invA, wy0 = (double)dx0 * invA;
  double wc0 = ((double)dy0 * (double)v1x - (double)dx0 * (double)v1y) * invA;
  double wx1 = -(double)dy1 * invA, wy1 = (double)dx1 * invA;
  double wc1 = ((double)dy1 * (double)v2x - (double)dx1 * (double)v2y) * invA;
  double wx2 = -(double)dy2 * invA, wy2 = (double)dx2 * invA;
  double wc2 = ((double)dy2 * (double)v0x - (double)dx2 * (double)v0y) * invA;
  double zx = wx0 * (double)c0z + wx1 * (double)c1z + wx2 * (double)c2z;
  double zy = wy0 * (double)c0z + wy1 * (double)c1z + wy2 * (double)c2z;
  double zc = wc0 * (double)c0z + wc1 * (double)c1z + wc2 * (double)c2z;
  double m0 = fabs(wx0) + fabs(wy0) + fabs(wc0);
  double m1 = fabs(wx1) + fabs(wy1) + fabs(wc1);
  double m2 = fabs(wx2) + fabs(wy2) + fabs(wc2);
  double mm = fmax(fmax(m0, m1), m2);
  float epsf = fmaxf((float)(6e-7 * mm), 3e-7f);
  float epsz = fmaxf((float)(1e-6 * (fabs(zx) + fabs(zy) + fabs(zc))), 1e-9f);

  if (epsf <= SLIV_EPS) {
    // ---- normal face: fast-path record + band mask ----
    FaceRec fr;
    fr.f[0] = (float)wx0; fr.f[1] = (float)wy0; fr.f[2] = (float)wc0;
    fr.f[3] = (float)wx1; fr.f[4] = (float)wy1; fr.f[5] = (float)wc1;
    fr.f[6] = (float)wx2; fr.f[7] = (float)wy2; fr.f[8] = (float)wc2;
    fr.f[9] = epsf; fr.f[10] = (float)zx; fr.f[11] = (float)zy;
    fr.f[12] = (float)zc; fr.f[13] = epsz;
    fr.f[14] = __int_as_float(f); fr.f[15] = 0.f;
    frec[i] = fr;
    // conservative y-row interval of the band-dilated triangle
    float band = fmaxf(0.302f, 1.5f * epsf);
    float ylo = -1.01f, yhi = 1.01f;
    bool empty = false;
    float wyA[3] = {fr.f[1], fr.f[4], fr.f[7]};
    float gA[3]  = {fr.f[2] + fabsf(fr.f[0]) + band,
                    fr.f[5] + fabsf(fr.f[3]) + band,
                    fr.f[8] + fabsf(fr.f[6]) + band};
#pragma unroll
    for (int e = 0; e < 3; ++e) {
      float wy = wyA[e], g = gA[e];
      if (wy > 1e-30f)       ylo = fmaxf(ylo, -g / wy);
      else if (wy < -1e-30f) yhi = fminf(yhi, -g / wy);
      else                   empty |= (g < 0.f);
      empty |= (g + fabsf(wy) < 0.f);
    }
    if (!empty && ylo <= yhi) {
      int r0 = max(0, (int)floorf((ylo + 1.0f) * 31.5f) - 1);
      int r1 = min(63, (int)ceilf((yhi + 1.0f) * 31.5f) + 1);
      if (r0 <= r1) {
        u64 bit = 1ull << (f & 63);
        int word = f >> 6;
        for (int bb = (r0 >> 2); bb <= (r1 >> 2); ++bb)
          atomicOr(&bandmask[((size_t)(b * 16 + bb)) * WPR + word], bit);
      }
    }
  } else {
    // ---- sliver: exact-f64 side path. y-interval from f64 w-coeffs, band=0.302 ----
    double ylo = -1.01, yhi = 1.01;
    bool empty = false;
    double wyA[3] = {wy0, wy1, wy2};
    double gA[3]  = {wc0 + fabs(wx0) + 0.302, wc1 + fabs(wx1) + 0.302,
                     wc2 + fabs(wx2) + 0.302};
#pragma unroll
    for (int e = 0; e < 3; ++e) {
      double wy = wyA[e], g = gA[e];
      if (wy > 1e-300)       ylo = fmax(ylo, -g / wy);
      else if (wy < -1e-300) yhi = fmin(yhi, -g / wy);
      else                   empty |= (g < 0.0);
      empty |= (g + fabs(wy) < 0.0);
    }
    if (!empty && ylo <= yhi) {
      int r0 = max(0, (int)floor((ylo + 1.0) * 31.5) - 1);
      int r1 = min(63, (int)ceil((yhi + 1.0) * 31.5) + 1);
      if (r0 <= r1) {
        int slot = atomicAdd(&slivcnt[b], 1);
        SlivRec s;
        int2 iv;
        memcpy(&iv, &invA, 8);
        s.g[0] = __int_as_float(iv.x); s.g[1] = __int_as_float(iv.y);
        s.g[2] = v0x; s.g[3] = v0y;
        s.g[4] = v1x; s.g[5] = v1y; s.g[6] = v2x; s.g[7] = v2y;
        s.g[8] = c0z; s.g[9] = c1z; s.g[10] = c2z;
        s.g[11] = __int_as_float(f);
        s.g[12] = __int_as_float(r0 | (r1 << 16));
        s.g[13] = 0.f; s.g[14] = 0.f; s.g[15] = 0.f;
        slivers[(size_t)b * F + slot] = s;
      }
    }
  }
  // face normal -> vertex normal scatter (f32 atomics)
  float e1x = cx[1] - cx[0], e1y = cy[1] - cy[0], e1z = cz[1] - cz[0];
  float e2x = cx[2] - cx[0], e2y = cy[2] - cy[0], e2z = cz[2] - cz[0];
  float nx = e1y * e2z - e1z * e2y;
  float ny = e1z * e2x - e1x * e2z;
  float nz = e1x * e2y - e1y * e2x;
#pragma unroll
  for (int k = 0; k < 3; ++k) {
    float* vn = vnorm + (size_t)(b * V + vid[k]) * 3;
    atomicAdd(vn + 0, nx); atomicAdd(vn + 1, ny); atomicAdd(vn + 2, nz);
  }
}

// bitmask -> compact ascending per-band face list. One wave per band.
__global__ __launch_bounds__(256) void k_bandlist(
    const u64* __restrict__ bandmask, int WPR,
    int* __restrict__ bandlist, int* __restrict__ bandcnt, int F, int NBAND) {
  int wid = __builtin_amdgcn_readfirstlane(threadIdx.x >> 6);
  int band = blockIdx.x * 4 + wid;
  if (band >= NBAND) return;
  int lane = threadIdx.x & 63;
  const u64* rm = bandmask + (size_t)band * WPR;
  int w0i = 2 * lane, w1i = 2 * lane + 1;       // lane order == word order
  u64 m0 = (w0i < WPR) ? rm[w0i] : 0ull;
  u64 m1 = (w1i < WPR) ? rm[w1i] : 0ull;
  int c = __popcll(m0) + __popcll(m1);
  int off = c;
  for (int d = 1; d < 64; d <<= 1) {
    int t = __shfl_up(off, d);
    if (lane >= d) off += t;
  }
  int pos = off - c;
  int* out = bandlist + (size_t)band * F;
  u64 m = m0;
  int base = w0i << 6;
  while (m) { int t = __builtin_ctzll(m); m &= m - 1; out[pos++] = base + t; }
  m = m1; base = w1i << 6;
  while (m) { int t = __builtin_ctzll(m); m &= m - 1; out[pos++] = base + t; }
  if (lane == 63) bandcnt[band] = off;
}

// LDS-staged raster: block = one 4-row band x 64 px; grid.y = NC chunks + 1 sliver pass
__global__ __launch_bounds__(256) void k_raster(
    const FaceRec* __restrict__ frec,
    const int* __restrict__ bandlist, const int* __restrict__ bandcnt,
    const SlivRec* __restrict__ slivers, const int* __restrict__ slivcnt,
    float4* __restrict__ ppart, int F, int P) {
  __shared__ float4 hot[256 * 3];
  __shared__ float4 cold[256];
  __shared__ int sr01[256];
  int band = blockIdx.x;
  int chunk = blockIdx.y;
  int b = band >> 4;
  int wid = __builtin_amdgcn_readfirstlane(threadIdx.x >> 6);
  int r = ((band & 15) << 2) + wid;            // wave-uniform row
  int x = threadIdx.x & 63;
  const double step = 2.0 / 63.0;
  double pxd = (x == HW - 1) ? 1.0 : (x * step - 1.0);
  double pyd = (r == HW - 1) ? 1.0 : (r * step - 1.0);
  float pxf = (float)pxd, pyf = (float)pyd;

  float zminf = INFINITY, weps = 0.f, lsum = 0.f;
  int best = 0;
  bool flag = false;

  if (chunk < NC) {
    int n = bandcnt[band];
    int c0 = (n * chunk) / NC;
    int c1 = (n * (chunk + 1)) / NC;
    const int* bl = bandlist + (size_t)band * F;
    const FaceRec* fb = frec + (size_t)b * F;
    for (int base = c0; base < c1; base += 256) {
      int nst = min(256, c1 - base);
      __syncthreads();
      int t = threadIdx.x;
      if (t < nst) {
        int fi = bl[base + t];                  // coalesced per-lane load
        const float4* pf = (const float4*)(fb + fi);  // per-lane gather, full BW
        float4 q0 = pf[0], q1 = pf[1], q2 = pf[2], q3 = pf[3];
        hot[t * 3 + 0] = q0; hot[t * 3 + 1] = q1; hot[t * 3 + 2] = q2;
        cold[t] = q3;
      }
      __syncthreads();
      for (int j = 0; j < nst; ++j) {          // wave-uniform LDS broadcast reads
        float4 q0 = hot[j * 3 + 0], q1 = hot[j * 3 + 1], q2 = hot[j * 3 + 2];
        float w0 = fmaf(q0.x, pxf, fmaf(q0.y, pyf, q0.z));
        float w1 = fmaf(q0.w, pxf, fmaf(q1.x, pyf, q1.y));
        float w2 = fmaf(q1.z, pxf, fmaf(q1.w, pyf, q2.x));
        float dmin = fminf(fminf(w0, w1), w2);
        if (dmin > -0.3f) {
          float tt = fminf(fmaxf(dmin * 100.0f, -30.0f), 0.0f);
          float pr = __expf(tt);               // inside -> tt=0 -> pr=1 exactly
          lsum += __logf(fmaf(-pr, 0.99999990f, 1.0f));
        }
        float epsf = q2.y;
        if (dmin > -epsf) {
          float4 q3 = cold[j];
          float z = fmaf(q2.z, pxf, fmaf(q2.w, pyf, q3.x));
          float epsz = q3.y;
          int fid = __float_as_int(q3.z);
          bool contend = (z < zminf + epsz + weps) & (z > -epsz);
          flag |= (fabsf(dmin) < epsf) & contend;
          flag |= (dmin >= 0.0f) & (fabsf(z) < epsz);
          flag |= (dmin >= 0.0f) & (z > 0.0f) & (fabsf(z - zminf) < epsz + weps);
          if ((dmin >= 0.0f) & (z > 0.0f) &
              ((z < zminf) | ((z == zminf) & (fid < best)))) {
            zminf = z; best = fid; weps = epsz;
          }
        }
      }
    }
  } else {
    // ---- exact-f64 sliver pass ----
    int ns = slivcnt[b];
    const SlivRec* sv = slivers + (size_t)b * F;
    for (int base = 0; base < ns; base += 256) {
      int nst = min(256, ns - base);
      __syncthreads();
      int t = threadIdx.x;
      if (t < nst) {
        const float4* ps = (const float4*)(sv + base + t);
        float4 q0 = ps[0], q1 = ps[1], q2 = ps[2], q3 = ps[3];
        hot[t * 3 + 0] = q0; hot[t * 3 + 1] = q1; hot[t * 3 + 2] = q2;
        sr01[t] = __float_as_int(q3.x);
      }
      __syncthreads();
      for (int j = 0; j < nst; ++j) {
        int rr = sr01[j];
        if (r < (rr & 0xffff) || r > (rr >> 16)) continue;   // wave-uniform skip
        float4 q0 = hot[j * 3 + 0], q1 = hot[j * 3 + 1], q2 = hot[j * 3 + 2];
        double invA = __hiloint2double(__float_as_int(q0.y), __float_as_int(q0.x));
        float v0x = q0.z, v0y = q0.w;
        float v1x = q1.x, v1y = q1.y, v2x = q1.z, v2y = q1.w;
        float z0 = q2.x, z1 = q2.y, z2 = q2.z;
        int fid = __float_as_int(q2.w);
        float dx0 = v2x - v1x, dy0 = v2y - v1y;
        float dx1 = v0x - v2x, dy1 = v0y - v2y;
        float dx2 = v1x - v0x, dy2 = v1y - v0y;
        double a0 = (double)dx0 * (pyd - (double)v1y) - (double)dy0 * (pxd - (double)v1x);
        double a1 = (double)dx1 * (pyd - (double)v2y) - (double)dy1 * (pxd - (double)v2x);
        double a2 = (double)dx2 * (pyd - (double)v0y) - (double)dy2 * (pxd - (double)v0x);
        double w0 = a0 * invA, w1 = a1 * invA, w2 = a2 * invA;
        double dmin = fmin(fmin(w0, w1), w2);
        if (dmin > -0.31) {
          double tt = fmin(fmax(dmin * 100.0, -30.0), 0.0);
          float pr = __expf((float)tt);        // inside -> tt=0 -> pr=1 exactly
          lsum += __logf(fmaf(-pr, 0.99999990f, 1.0f));
        }
        bool inside = (w0 >= 0.0) & (w1 >= 0.0) & (w2 >= 0.0);
        double z = (w0 * (double)z0 + w1 * (double)z1) + w2 * (double)z2;
        if (inside & (z > 0.0)) {
          float zf = (float)z;
          flag |= fabsf(zf - zminf) < (2e-6f + weps);
          if ((zf < zminf) | ((zf == zminf) & (fid < best))) {
            zminf = zf; best = fid; weps = 2e-6f;
          }
        }
      }
    }
  }
  int p = b * (HW * HW) + r * HW + x;
  unsigned bestflag = (unsigned)best | (flag ? 0x80000000u : 0u);
  ppart[(size_t)chunk * P + p] = make_float4(zminf, __uint_as_float(bestflag), lsum, weps);
}

// exact f64 winner recompute + gather-interpolate + output write (not improb)
__device__ void write_winner(const FaceGeo* __restrict__ fgeo,
                             const int* __restrict__ faces,
                             const float* __restrict__ vnorm,
                             const float* __restrict__ attribs,
                             float* __restrict__ out, int P,
                             int b, int V, int F, int pix,
                             int best, bool covered) {
  int p = b * (HW * HW) + pix;
  float imn[3] = {0.f, 0.f, 0.f};
  float ima[3] = {0.f, 0.f, 0.f};
  if (covered) {
    int x = pix & 63, y = pix >> 6;
    const double step = 2.0 / 63.0;
    double px = (x == HW - 1) ? 1.0 : (x * step - 1.0);
    double py = (y == HW - 1) ? 1.0 : (y * step - 1.0);
    FaceGeo g = fgeo[(size_t)b * F + best];
    float dx0 = g.v2x - g.v1x, dy0 = g.v2y - g.v1y;
    float dx1 = g.v0x - g.v2x, dy1 = g.v0y - g.v2y;
    float dx2 = g.v1x - g.v0x, dy2 = g.v1y - g.v0y;
    float A = dx2 * (g.v2y - g.v0y) - dy2 * (g.v2x - g.v0x);
    if (fabsf(A) < 1e-8f) A = 1e-8f;
    double invA = 1.0 / (double)A;
    double a0 = (double)dx0 * (py - (double)g.v1y) - (double)dy0 * (px - (double)g.v1x);
    double a1 = (double)dx1 * (py - (double)g.v2y) - (double)dy1 * (px - (double)g.v2x);
    double a2 = (double)dx2 * (py - (double)g.v0y) - (double)dy2 * (px - (double)g.v0x);
    double wk[3] = {a0 * invA, a1 * invA, a2 * invA};
    int vid[3] = {faces[best * 3 + 0], faces[best * 3 + 1], faces[best * 3 + 2]};
    double v[6] = {0, 0, 0, 0, 0, 0};
#pragma unroll
    for (int k = 0; k < 3; ++k) {
      const float* n = vnorm + (size_t)(b * V + vid[k]) * 3;
      float nx = n[0], ny = n[1], nz = n[2];
      float nrm = sqrtf(nx * nx + ny * ny + nz * nz) + 1e-10f;
      const float* at = attribs + (((size_t)(b * F + best)) * 3 + k) * 3;
      v[0] += wk[k] * (double)(nx / nrm);
      v[1] += wk[k] * (double)(ny / nrm);
      v[2] += wk[k] * (double)(nz / nrm);
      v[3] += wk[k] * (double)at[0];
      v[4] += wk[k] * (double)at[1];
      v[5] += wk[k] * (double)at[2];
    }
    double nn = sqrt(v[0] * v[0] + v[1] * v[1] + v[2] * v[2]) + 1e-10;
    imn[0] = (float)(v[0] / nn);
    imn[1] = (float)(v[1] / nn);
    imn[2] = (float)(v[2] / nn);
    ima[0] = (float)v[3]; ima[1] = (float)v[4]; ima[2] = (float)v[5];
  }
  float* o_n = out;
  float* o_a = out + (size_t)P * 3;
  float* o_p = out + (size_t)P * 6;
  float* o_i = o_p + P;
  o_n[(size_t)p * 3 + 0] = imn[0];
  o_n[(size_t)p * 3 + 1] = imn[1];
  o_n[(size_t)p * 3 + 2] = imn[2];
  o_a[(size_t)p * 3 + 0] = ima[0];
  o_a[(size_t)p * 3 + 1] = ima[1];
  o_a[(size_t)p * 3 + 2] = ima[2];
  o_i[p] = covered ? (float)best : -1.0f;
}

__global__ __launch_bounds__(256) void k_final(
    const FaceGeo* __restrict__ fgeo,
    const int* __restrict__ faces,
    const float* __restrict__ vnorm,
    const float* __restrict__ attribs,
    const float4* __restrict__ ppart,
    float* __restrict__ out,
    int* __restrict__ cnt, int* __restrict__ list,
    int B, int V, int F) {
  int p = blockIdx.x * blockDim.x + threadIdx.x;
  int P = B * HW * HW;
  if (p >= P) return;
  float zmin = INFINITY, weps = 0.f, lsum = 0.f;
  int best = 0x7fffffff;
  bool flag = false;
  for (int c = 0; c < NC + 1; ++c) {
    float4 q = ppart[(size_t)c * P + p];
    float z = q.x;
    unsigned pb = __float_as_uint(q.y);
    int id = (int)(pb & 0x7fffffffu);
    float e = q.w;
    flag |= (pb >> 31) != 0;
    flag |= fabsf(z - zmin) < (e + weps + 1e-5f);   // near-tie (INF-safe)
    if ((z < zmin) | ((z == zmin) & (id < best))) { zmin = z; best = id; weps = e; }
    lsum += q.z;
  }
  bool covered = (zmin < 1e38f);
  int b = p >> 12;
  int pix = p & 4095;
  write_winner(fgeo, faces, vnorm, attribs, out, P, b, V, F, pix,
               covered ? best : 0, covered);
  float* o_p = out + (size_t)P * 6;
  o_p[p] = 1.0f - __expf(lsum);
  if (flag) {
    int s = atomicAdd(cnt, 1);
    list[s] = p;
  }
}

// exact f64 re-argmin for flagged pixels: one wave per pixel; band list + slivers
__global__ __launch_bounds__(256) void k_repair(
    const FaceGeo* __restrict__ fgeo,
    const int* __restrict__ faces,
    const float* __restrict__ vnorm,
    const float* __restrict__ attribs,
    const int* __restrict__ bandlist, const int* __restrict__ bandcnt,
    const SlivRec* __restrict__ slivers, const int* __restrict__ slivcnt,
    const int* __restrict__ cnt, const int* __restrict__ list,
    float* __restrict__ out, int B, int V, int F) {
  int P = B * HW * HW;
  int lane = threadIdx.x & 63;
  int wid = (blockIdx.x * blockDim.x + threadIdx.x) >> 6;
  int nwaves = (gridDim.x * blockDim.x) >> 6;
  int n = cnt[0];
  for (int i = wid; i < n; i += nwaves) {
    int p = list[i];
    int b = p >> 12;
    int pix = p & 4095;
    int x = pix & 63, y = pix >> 6;
    int band = b * 16 + (y >> 2);
    const double step = 2.0 / 63.0;
    double px = (x == HW - 1) ? 1.0 : (x * step - 1.0);
    double py = (y == HW - 1) ? 1.0 : (y * step - 1.0);
    const int* bl = bandlist + (size_t)band * F;
    int m = bandcnt[band];
    double zmin = INFINITY;
    int best = 0x7fffffff;
    for (int k = lane; k < m; k += 64) {
      int f = bl[k];
      FaceGeo g = fgeo[(size_t)b * F + f];
      float dx0 = g.v2x - g.v1x, dy0 = g.v2y - g.v1y;
      float dx1 = g.v0x - g.v2x, dy1 = g.v0y - g.v2y;
      float dx2 = g.v1x - g.v0x, dy2 = g.v1y - g.v0y;
      float A = dx2 * (g.v2y - g.v0y) - dy2 * (g.v2x - g.v0x);
      if (fabsf(A) < 1e-8f) A = 1e-8f;
      double invA = 1.0 / (double)A;
      double a0 = (double)dx0 * (py - (double)g.v1y) - (double)dy0 * (px - (double)g.v1x);
      double a1 = (double)dx1 * (py - (double)g.v2y) - (double)dy1 * (px - (double)g.v2x);
      double a2 = (double)dx2 * (py - (double)g.v0y) - (double)dy2 * (px - (double)g.v0x);
      double w0 = a0 * invA, w1 = a1 * invA, w2 = a2 * invA;
      bool inside = (w0 >= 0.0) & (w1 >= 0.0) & (w2 >= 0.0);
      double z = (w0 * (double)g.z0 + w1 * (double)g.z1) + w2 * (double)g.z2;
      if (inside & (z > 0.0) &
          ((z < zmin) | ((z == zmin) & (f < best)))) { zmin = z; best = f; }
    }
    int ns = slivcnt[b];
    const SlivRec* sv = slivers + (size_t)b * F;
    for (int k = lane; k < ns; k += 64) {
      const SlivRec s = sv[k];
      int rr = __float_as_int(s.g[12]);
      if (y < (rr & 0xffff) || y > (rr >> 16)) continue;
      double invA = __hiloint2double(__float_as_int(s.g[1]), __float_as_int(s.g[0]));
      float v0x = s.g[2], v0y = s.g[3], v1x = s.g[4], v1y = s.g[5];
      float v2x = s.g[6], v2y = s.g[7], z0 = s.g[8], z1 = s.g[9], z2 = s.g[10];
      int fid = __float_as_int(s.g[11]);
      float dx0 = v2x - v1x, dy0 = v2y - v1y;
      float dx1 = v0x - v2x, dy1 = v0y - v2y;
      float dx2 = v1x - v0x, dy2 = v1y - v0y;
      double a0 = (double)dx0 * (py - (double)v1y) - (double)dy0 * (px - (double)v1x);
      double a1 = (double)dx1 * (py - (double)v2y) - (double)dy1 * (px - (double)v2x);
      double a2 = (double)dx2 * (py - (double)v0y) - (double)dy2 * (px - (double)v0x);
      double w0 = a0 * invA, w1 = a1 * invA, w2 = a2 * invA;
      bool inside = (w0 >= 0.0) & (w1 >= 0.0) & (w2 >= 0.0);
      double z = (w0 * (double)z0 + w1 * (double)z1) + w2 * (double)z2;
      if (inside & (z > 0.0) &
          ((z < zmin) | ((z == zmin) & (fid < best)))) { zmin = z; best = fid; }
    }
    // lexicographic (z, idx) wave reduce
    for (int off = 32; off; off >>= 1) {
      double zo = __shfl_down(zmin, off);
      int bo = __shfl_down(best, off);
      if ((zo < zmin) || ((zo == zmin) && (bo < best))) { zmin = zo; best = bo; }
    }
    if (lane == 0) {
      bool covered = (zmin < 1e300);
      write_winner(fgeo, faces, vnorm, attribs, out, P, b, V, F, pix,
                   covered ? best : 0, covered);
    }
  }
}

extern "C" void kernel_launch(void* const* d_in, const int* in_sizes, int n_in,
                              void* d_out, int out_size, void* d_ws, size_t ws_size,
                              hipStream_t stream) {
  const float* vert    = (const float*)d_in[0];
  const int*   faces   = (const int*)d_in[1];
  const float* attribs = (const float*)d_in[2];
  const float* rot     = (const float*)d_in[3];
  const float* trans   = (const float*)d_in[4];
  int B = in_sizes[4] / 3;
  int V = in_sizes[0] / (3 * B);
  int F = in_sizes[1] / 3;
  int P = B * HW * HW;
  int NBAND = B * 16;
  int WPR = (F + 63) / 64;
  int maskwords = NBAND * WPR;

  char* w = (char*)d_ws;
  FaceRec* frec   = (FaceRec*)w;  w += sizeof(FaceRec) * (size_t)B * F;   // 64B-aligned
  SlivRec* slivers= (SlivRec*)w;  w += sizeof(SlivRec) * (size_t)B * F;
  FaceGeo* fgeo   = (FaceGeo*)w;  w += sizeof(FaceGeo) * (size_t)B * F;
  float4* ppart   = (float4*)w;   w += 16u * (size_t)P * (NC + 1);
  u64* bandmask   = (u64*)w;      w += 8u * (size_t)maskwords;
  int* bandlist   = (int*)w;      w += 4u * (size_t)NBAND * F;
  int* bandcnt    = (int*)w;      w += 4u * (size_t)NBAND;
  int* slivcnt    = (int*)w;      w += 4u * (size_t)B;
  float* vnorm    = (float*)w;    w += 4u * 3 * (size_t)B * V;
  int* cnt        = (int*)w;      w += 4;
  int* list       = (int*)w;      w += 4u * (size_t)P;

  k_zero<<<64, 256, 0, stream>>>(vnorm, B * V * 3, bandmask, maskwords, slivcnt, B, cnt);
  k_facepre<<<(B * F + 255) / 256, 256, 0, stream>>>(
      vert, rot, trans, faces, frec, fgeo, bandmask, WPR, slivers, slivcnt,
      vnorm, B, V, F);
  k_bandlist<<<(NBAND + 3) / 4, 256, 0, stream>>>(bandmask, WPR, bandlist, bandcnt,
                                                  F, NBAND);
  dim3 rg((unsigned)NBAND, (unsigned)(NC + 1));
  k_raster<<<rg, 256, 0, stream>>>(frec, bandlist, bandcnt, slivers, slivcnt,
                                   ppart, F, P);
  k_final<<<(P + 255) / 256, 256, 0, stream>>>(fgeo, faces, vnorm, attribs, ppart,
                                               (float*)d_out, cnt, list, B, V, F);
  k_repair<<<64, 256, 0, stream>>>(fgeo, faces, vnorm, attribs, bandlist, bandcnt,
                                   slivers, slivcnt, cnt, list,
                                   (float*)d_out, B, V, F);
}